// Round 12
// baseline (230.457 us; speedup 1.0000x reference)
//
#include <hip/hip_runtime.h>
#include <hip/hip_fp16.h>

// 2-layer GAT, H=2 heads, D=64 per head, F_IN=128.
// R12: GEMM blocks cover 128 rows (2x64 subtiles sharing one staged W copy):
// halves W-staging traffic and block count. Rest as R11: memset -> prepcount ->
// bscan -> [gemm1 ∥ bucket] -> build -> agg1 -> gemm2 -> agg2.
// agg (at pattern floor, 69us): 4 nodes/wave, 16 lanes/node, unnormalized-exp
// records in LDS, 4-record gather batches.
// Assumes N <= 131072 (src packs in 17 bits) and NBUCK <= 512.

#define NEG_SLOPE 0.2f
#define BSHIFT 8
#define ETILE 4096

typedef _Float16 half8_t __attribute__((ext_vector_type(8)));
typedef float f32x4_t __attribute__((ext_vector_type(4)));
typedef unsigned long long u64;

// ---------------- prep (W transpose+fp16+pre-swizzle) + dst histogram ----------------

__global__ __launch_bounds__(256) void k_prepcount(const float* __restrict__ W1,
                                                   const float* __restrict__ W2,
                                                   __half* __restrict__ wh1,
                                                   __half* __restrict__ wh2,
                                                   const int* __restrict__ dst, int E,
                                                   int nbuck, int* __restrict__ bcnt) {
    int b = blockIdx.x;
    int t = threadIdx.x;
    if (b < 16) {
        const float* W = (b < 8) ? W1 : W2;
        __half* Wh = (b < 8) ? wh1 : wh2;
        int q = (b & 7) * 256 + t;
        int r = q >> 4;
        int c = q & 15;
        int cl = c ^ (r & 7);
        float f[8];
        #pragma unroll
        for (int j = 0; j < 8; j++) f[j] = W[(size_t)(cl * 8 + j) * 128 + r];
        __half2 h0 = __floats2half2_rn(f[0], f[1]);
        __half2 h1 = __floats2half2_rn(f[2], f[3]);
        __half2 h2 = __floats2half2_rn(f[4], f[5]);
        __half2 h3 = __floats2half2_rn(f[6], f[7]);
        uint4 pk;
        pk.x = *(unsigned*)&h0;
        pk.y = *(unsigned*)&h1;
        pk.z = *(unsigned*)&h2;
        pk.w = *(unsigned*)&h3;
        *(uint4*)((char*)Wh + (size_t)q * 16) = pk;
    } else {
        __shared__ int cnt[512];
        for (int i = t; i < nbuck; i += 256) cnt[i] = 0;
        __syncthreads();
        int e0 = (b - 16) * ETILE;
        #pragma unroll
        for (int j = 0; j < ETILE / 256; j++) {
            int e = e0 + j * 256 + t;
            if (e < E) atomicAdd(&cnt[dst[e] >> BSHIFT], 1);
        }
        __syncthreads();
        for (int i = t; i < nbuck; i += 256) {
            int c = cnt[i];
            if (c > 0) atomicAdd(&bcnt[i], c);
        }
    }
}

// ---------------- bucket scan ----------------

__global__ __launch_bounds__(256) void k_bscan(const int* __restrict__ bcnt, int nbuck,
                                               int* __restrict__ bbase,
                                               int* __restrict__ bcursor,
                                               int* __restrict__ rowStart, int N, int E) {
    __shared__ int sa[512], sb[512];
    int t = threadIdx.x;
    sa[t] = (t < nbuck) ? bcnt[t] : 0;
    sa[t + 256] = (t + 256 < nbuck) ? bcnt[t + 256] : 0;
    __syncthreads();
    int* a = sa;
    int* b = sb;
    for (int off = 1; off < 512; off <<= 1) {
        b[t] = a[t] + ((t >= off) ? a[t - off] : 0);
        int i = t + 256;
        b[i] = a[i] + ((i >= off) ? a[i - off] : 0);
        __syncthreads();
        int* tmp = a; a = b; b = tmp;
    }
    #pragma unroll
    for (int k = 0; k < 2; k++) {
        int i = t + k * 256;
        if (i <= nbuck) {
            int e_ = (i == 0) ? 0 : a[i - 1];
            bbase[i] = e_;
            if (i < nbuck) bcursor[i] = e_;
        }
    }
    if (t == 0) rowStart[N] = E;
}

// ---------------- build (per-bucket counting sort) ----------------

__global__ __launch_bounds__(256) void k_build(const int* __restrict__ ebuf,
                                               const int* __restrict__ bbase,
                                               int* __restrict__ rowStart,
                                               int* __restrict__ csr, int N) {
    __shared__ int dcnt[256];
    __shared__ int sa[256], sb[256];
    __shared__ int cur[256];
    int b = blockIdx.x;
    int t = threadIdx.x;
    int lo = bbase[b], hi = bbase[b + 1];
    int n0 = b << BSHIFT;
    dcnt[t] = 0;
    __syncthreads();
    for (int p = lo + t; p < hi; p += 256)
        atomicAdd(&dcnt[((unsigned)ebuf[p]) >> 17], 1);
    __syncthreads();
    sa[t] = dcnt[t];
    __syncthreads();
    int* a = sa;
    int* bq = sb;
    for (int off = 1; off < 256; off <<= 1) {
        bq[t] = a[t] + ((t >= off) ? a[t - off] : 0);
        __syncthreads();
        int* tmp = a; a = bq; bq = tmp;
    }
    int excl = (t == 0) ? 0 : a[t - 1];
    int pos0 = lo + excl;
    if (n0 + t < N) rowStart[n0 + t] = pos0;
    cur[t] = pos0;
    __syncthreads();
    for (int p = lo + t; p < hi; p += 256) {
        int v = ebuf[p];
        int pos = atomicAdd(&cur[((unsigned)v) >> 17], 1);
        csr[pos] = v & 0x1FFFF;
    }
}

// ---------------- fused MFMA GEMM: 128 rows/block (+ optional bucket side-job) ----------------

__device__ __forceinline__ void g2l16(const void* g, void* l) {
    __builtin_amdgcn_global_load_lds((const __attribute__((address_space(1))) void*)g,
                                     (__attribute__((address_space(3))) void*)l, 16, 0, 0);
}

template <bool FP16IN, bool BUCKET>
__global__ __launch_bounds__(256, 2) void k_gemm_fused(const void* __restrict__ Ain,
                                                       const __half* __restrict__ WhT,
                                                       __half* __restrict__ hb,
                                                       const float* __restrict__ al,
                                                       const float* __restrict__ ar,
                                                       float* __restrict__ el,
                                                       float* __restrict__ er, int M,
                                                       const int* __restrict__ srcE,
                                                       const int* __restrict__ dstE, int E,
                                                       int nbuck, int* __restrict__ bcursor,
                                                       int* __restrict__ ebuf,
                                                       int bucketBlocks) {
    __shared__ __half xs[128 * 128];   // 32 KB, swizzled (bucket path aliases this)
    __shared__ __half ws[128 * 128];   // 32 KB, swizzled (pre-swizzled source)
    int t = threadIdx.x;

    if (BUCKET && (int)blockIdx.x < bucketBlocks) {
        // ---- bucket side-job (runs concurrent with gemm blocks) ----
        int* cnt = (int*)xs;           // 512 ints
        int* base = cnt + 512;         // 512 ints
        for (int b = t; b < nbuck; b += 256) cnt[b] = 0;
        __syncthreads();
        int e0 = (int)blockIdx.x * ETILE;
        int dv[ETILE / 256], sv[ETILE / 256];
        #pragma unroll
        for (int j = 0; j < ETILE / 256; j++) {
            int e = e0 + j * 256 + t;
            dv[j] = -1;
            if (e < E) {
                dv[j] = dstE[e];
                sv[j] = srcE[e];
                atomicAdd(&cnt[dv[j] >> BSHIFT], 1);
            }
        }
        __syncthreads();
        for (int b = t; b < nbuck; b += 256) {
            int c = cnt[b];
            base[b] = (c > 0) ? atomicAdd(&bcursor[b], c) : 0;
        }
        __syncthreads();
        for (int b = t; b < nbuck; b += 256) cnt[b] = 0;
        __syncthreads();
        #pragma unroll
        for (int j = 0; j < ETILE / 256; j++) {
            if (dv[j] >= 0) {
                int bk = dv[j] >> BSHIFT;
                int r = atomicAdd(&cnt[bk], 1);
                ebuf[base[bk] + r] = sv[j] | ((dv[j] & ((1 << BSHIFT) - 1)) << 17);
            }
        }
        return;
    }

    int row0 = (BUCKET ? ((int)blockIdx.x - bucketBlocks) : (int)blockIdx.x) * 128;

    // stage whole W (pre-swizzled): 2048 x 16B, 8/thread
    for (int j = 0; j < 8; j++) {
        int c16 = t + j * 256;
        g2l16((const char*)WhT + (size_t)c16 * 16, (char*)ws + (size_t)c16 * 16);
    }
    // stage A: 128 rows
    if (FP16IN) {
        const char* Ah = (const char*)Ain;   // pre-swizzled fp16 rows (padded buffer)
        for (int j = 0; j < 8; j++) {
            int c16 = t + j * 256;
            g2l16(Ah + (size_t)row0 * 256 + (size_t)c16 * 16, (char*)xs + (size_t)c16 * 16);
        }
    } else {
        const float* A = (const float*)Ain;
        for (int j = 0; j < 16; j++) {
            int f4 = t + j * 256;            // 4096 float4
            int r = f4 >> 5;                 // 0..127
            int gr = row0 + r;
            if (gr >= M) gr = M - 1;         // clamp; outputs guarded
            float4 v = ((const float4*)(A + (size_t)gr * 128))[f4 & 31];
            __half2 h0 = __floats2half2_rn(v.x, v.y);
            __half2 h1 = __floats2half2_rn(v.z, v.w);
            uint2 pk;
            pk.x = *(unsigned*)&h0;
            pk.y = *(unsigned*)&h1;
            int h8 = f4 & 31;
            int c = h8 >> 1, hh = h8 & 1;
            int addr8 = r * 32 + (c ^ (r & 7)) * 2 + hh;
            *(uint2*)((char*)xs + (size_t)addr8 * 8) = pk;
        }
    }
    __syncthreads();   // the only barrier

    int wid = t >> 6, lane = t & 63;
    int l15 = lane & 15;
    int g = lane >> 4;

    #pragma unroll
    for (int sub = 0; sub < 2; sub++) {
        int mrow = sub * 64 + wid * 16 + l15;

        half8_t xf[4];
        #pragma unroll
        for (int ks = 0; ks < 4; ks++) {
            int c = ks * 4 + g;
            xf[ks] = *(const half8_t*)((const char*)xs + mrow * 256 + (size_t)(c ^ (mrow & 7)) * 16);
        }

        f32x4_t acc[8];
        #pragma unroll
        for (int i = 0; i < 8; i++) acc[i] = (f32x4_t){0.f, 0.f, 0.f, 0.f};

        #pragma unroll
        for (int nt = 0; nt < 8; nt++) {
            int nrow = nt * 16 + l15;
            #pragma unroll
            for (int ks = 0; ks < 4; ks++) {
                int c = ks * 4 + g;
                half8_t wf = *(const half8_t*)((const char*)ws + nrow * 256 + (size_t)(c ^ (nrow & 7)) * 16);
                acc[nt] = __builtin_amdgcn_mfma_f32_16x16x32_f16(wf, xf[ks], acc[nt], 0, 0, 0);
            }
        }

        int m = row0 + mrow;
        bool valid = m < M;
        float plh0 = 0.f, prh0 = 0.f, plh1 = 0.f, prh1 = 0.f;
        #pragma unroll
        for (int nt = 0; nt < 8; nt++) {
            int col0 = nt * 16 + g * 4;
            if (valid) {
                __half2 p0 = __floats2half2_rn(acc[nt][0], acc[nt][1]);
                __half2 p1 = __floats2half2_rn(acc[nt][2], acc[nt][3]);
                uint2 pk;
                pk.x = *(unsigned*)&p0;
                pk.y = *(unsigned*)&p1;
                *(uint2*)(hb + (size_t)m * 128 + col0) = pk;
            }
            float4 alv = *(const float4*)(al + col0);
            float4 arv = *(const float4*)(ar + col0);
            float pl = acc[nt][0] * alv.x + acc[nt][1] * alv.y + acc[nt][2] * alv.z + acc[nt][3] * alv.w;
            float pr = acc[nt][0] * arv.x + acc[nt][1] * arv.y + acc[nt][2] * arv.z + acc[nt][3] * arv.w;
            if (nt < 4) { plh0 += pl; prh0 += pr; }
            else       { plh1 += pl; prh1 += pr; }
        }
        plh0 += __shfl_xor(plh0, 16); plh0 += __shfl_xor(plh0, 32);
        plh1 += __shfl_xor(plh1, 16); plh1 += __shfl_xor(plh1, 32);
        prh0 += __shfl_xor(prh0, 16); prh0 += __shfl_xor(prh0, 32);
        prh1 += __shfl_xor(prh1, 16); prh1 += __shfl_xor(prh1, 32);
        if (lane < 16 && valid) {
            el[m * 2 + 0] = plh0;
            el[m * 2 + 1] = plh1;
            er[m * 2 + 0] = prh0;
            er[m * 2 + 1] = prh1;
        }
    }
}

// ---------------- aggregate (pattern-floor pinned; unchanged from R11) ----------------

__device__ __forceinline__ float h2f(__half h) { return __half2float(h); }

template <bool RELU, bool FP16OUT>
__global__ __launch_bounds__(256) void k_agg(const __half* __restrict__ hb,
                                             const float* __restrict__ el,
                                             const float* __restrict__ er,
                                             const int* __restrict__ rowStart,
                                             const int* __restrict__ csr,
                                             const float* __restrict__ bias,
                                             void* __restrict__ outv, int N) {
    __shared__ u64 albuf[4][4][65];
    int wid = threadIdx.x >> 6;
    int lane = threadIdx.x & 63;
    int q = lane >> 4;    // node slot
    int l = lane & 15;    // lane within node: dims 8l..8l+7
    int n = (blockIdx.x * 4 + wid) * 4 + q;
    bool active = n < N;

    int rs = 0, deg = 0;
    float2 erv = make_float2(0.f, 0.f);
    if (active) {
        rs = rowStart[n];
        deg = rowStart[n + 1] - rs;
        erv = ((const float2*)er)[n];
    }

    float s0 = 0.f, s1 = 0.f;
    if (active) {
        for (int i = l; i <= deg; i += 16) {
            int s = (i == deg) ? n : csr[rs + i];
            float2 ev = ((const float2*)el)[s];
            float e0 = ev.x + erv.x;
            e0 = (e0 >= 0.f) ? e0 : NEG_SLOPE * e0;
            float e1 = ev.y + erv.y;
            e1 = (e1 >= 0.f) ? e1 : NEG_SLOPE * e1;
            float ex0 = __expf(e0);
            float ex1 = __expf(e1);
            s0 += ex0;
            s1 += ex1;
            if (i < 64) {
                __half2 eh = __floats2half2_rn(ex0, ex1);
                albuf[wid][q][i] = ((u64)(*(unsigned*)&eh) << 32) | (u64)(unsigned)s;
            }
        }
    }
    #pragma unroll
    for (int mk = 8; mk >= 1; mk >>= 1) {
        s0 += __shfl_xor(s0, mk);
        s1 += __shfl_xor(s1, mk);
    }
    bool hi = l >= 8;
    float invh = hi ? (1.0f / s1) : (1.0f / s0);

    float a0 = 0.f, a1 = 0.f, a2 = 0.f, a3 = 0.f;
    float a4 = 0.f, a5 = 0.f, a6 = 0.f, a7 = 0.f;
    if (active) {
        int cnt = deg + 1;
        int jmax = (cnt < 64) ? cnt : 64;
        int j = 0;
        for (; j + 4 <= jmax; j += 4) {
            u64 r0 = albuf[wid][q][j + 0];
            u64 r1 = albuf[wid][q][j + 1];
            u64 r2 = albuf[wid][q][j + 2];
            u64 r3 = albuf[wid][q][j + 3];
            uint4 v0 = ((const uint4*)(hb + (size_t)(unsigned)r0 * 128))[l];
            uint4 v1 = ((const uint4*)(hb + (size_t)(unsigned)r1 * 128))[l];
            uint4 v2 = ((const uint4*)(hb + (size_t)(unsigned)r2 * 128))[l];
            uint4 v3 = ((const uint4*)(hb + (size_t)(unsigned)r3 * 128))[l];
            #pragma unroll
            for (int kk = 0; kk < 4; kk++) {
                u64 rec = (kk == 0) ? r0 : (kk == 1) ? r1 : (kk == 2) ? r2 : r3;
                uint4 hv = (kk == 0) ? v0 : (kk == 1) ? v1 : (kk == 2) ? v2 : v3;
                unsigned eb = (unsigned)(rec >> 32);
                __half hx;
                *(unsigned short*)&hx = (unsigned short)(hi ? (eb >> 16) : (eb & 0xffff));
                float a = h2f(hx);
                __half2 p0 = *(__half2*)&hv.x;
                __half2 p1 = *(__half2*)&hv.y;
                __half2 p2 = *(__half2*)&hv.z;
                __half2 p3 = *(__half2*)&hv.w;
                a0 += a * h2f(p0.x);  a1 += a * h2f(p0.y);
                a2 += a * h2f(p1.x);  a3 += a * h2f(p1.y);
                a4 += a * h2f(p2.x);  a5 += a * h2f(p2.y);
                a6 += a * h2f(p3.x);  a7 += a * h2f(p3.y);
            }
        }
        for (; j < jmax; ++j) {
            u64 rec = albuf[wid][q][j];
            unsigned eb = (unsigned)(rec >> 32);
            __half hx;
            *(unsigned short*)&hx = (unsigned short)(hi ? (eb >> 16) : (eb & 0xffff));
            float a = h2f(hx);
            uint4 hv = ((const uint4*)(hb + (size_t)(unsigned)rec * 128))[l];
            __half2 p0 = *(__half2*)&hv.x;
            __half2 p1 = *(__half2*)&hv.y;
            __half2 p2 = *(__half2*)&hv.z;
            __half2 p3 = *(__half2*)&hv.w;
            a0 += a * h2f(p0.x);  a1 += a * h2f(p0.y);
            a2 += a * h2f(p1.x);  a3 += a * h2f(p1.y);
            a4 += a * h2f(p2.x);  a5 += a * h2f(p2.y);
            a6 += a * h2f(p3.x);  a7 += a * h2f(p3.y);
        }
        for (int jj = 64; jj < cnt; ++jj) {   // rare tail (deg >= 64)
            int s = (jj == deg) ? n : csr[rs + jj];
            float2 ev = ((const float2*)el)[s];
            float e = hi ? (ev.y + erv.y) : (ev.x + erv.x);
            e = (e >= 0.f) ? e : NEG_SLOPE * e;
            float a = __expf(e);
            uint4 hv = ((const uint4*)(hb + (size_t)s * 128))[l];
            __half2 p0 = *(__half2*)&hv.x;
            __half2 p1 = *(__half2*)&hv.y;
            __half2 p2 = *(__half2*)&hv.z;
            __half2 p3 = *(__half2*)&hv.w;
            a0 += a * h2f(p0.x);  a1 += a * h2f(p0.y);
            a2 += a * h2f(p1.x);  a3 += a * h2f(p1.y);
            a4 += a * h2f(p2.x);  a5 += a * h2f(p2.y);
            a6 += a * h2f(p3.x);  a7 += a * h2f(p3.y);
        }

        const float4* bp = (const float4*)(bias + l * 8);
        float4 b0 = bp[0], b1 = bp[1];
        a0 = a0 * invh + b0.x;  a1 = a1 * invh + b0.y;
        a2 = a2 * invh + b0.z;  a3 = a3 * invh + b0.w;
        a4 = a4 * invh + b1.x;  a5 = a5 * invh + b1.y;
        a6 = a6 * invh + b1.z;  a7 = a7 * invh + b1.w;
        if (RELU) {
            a0 = fmaxf(a0, 0.f); a1 = fmaxf(a1, 0.f); a2 = fmaxf(a2, 0.f); a3 = fmaxf(a3, 0.f);
            a4 = fmaxf(a4, 0.f); a5 = fmaxf(a5, 0.f); a6 = fmaxf(a6, 0.f); a7 = fmaxf(a7, 0.f);
        }
        if (FP16OUT) {
            __half2 q0 = __floats2half2_rn(a0, a1);
            __half2 q1 = __floats2half2_rn(a2, a3);
            __half2 q2 = __floats2half2_rn(a4, a5);
            __half2 q3 = __floats2half2_rn(a6, a7);
            uint4 opk;
            opk.x = *(unsigned*)&q0;
            opk.y = *(unsigned*)&q1;
            opk.z = *(unsigned*)&q2;
            opk.w = *(unsigned*)&q3;
            ((uint4*)((__half*)outv + (size_t)n * 128))[l ^ (n & 7)] = opk;
        } else {
            float* op = (float*)outv + (size_t)n * 128 + l * 8;
            ((float4*)op)[0] = make_float4(a0, a1, a2, a3);
            ((float4*)op)[1] = make_float4(a4, a5, a6, a7);
        }
    }
}

// ---------------- launcher ----------------

static inline size_t align_up(size_t v, size_t a) { return (v + a - 1) & ~(a - 1); }

extern "C" void kernel_launch(void* const* d_in, const int* in_sizes, int n_in,
                              void* d_out, int out_size, void* d_ws, size_t ws_size,
                              hipStream_t stream) {
    const float* x   = (const float*)d_in[0];
    const int*   src = (const int*)d_in[1];
    const int*   dst = (const int*)d_in[2];
    const float* W1  = (const float*)d_in[3];
    const float* al1 = (const float*)d_in[4];
    const float* ar1 = (const float*)d_in[5];
    const float* b1  = (const float*)d_in[6];
    const float* W2  = (const float*)d_in[7];
    const float* al2 = (const float*)d_in[8];
    const float* ar2 = (const float*)d_in[9];
    const float* b2  = (const float*)d_in[10];
    float* out = (float*)d_out;

    const int N = in_sizes[0] / 128;
    const int E = in_sizes[1];
    const int NBUCK = (N + 255) >> 8;

    char* ws = (char*)d_ws;
    size_t off = 0;
    __half* bufBh = (__half*)(ws + off); off = align_up(off + (size_t)N * 128 * 2 + 32768, 256);
    __half* hb    = (__half*)(ws + off); off = align_up(off + (size_t)N * 128 * 2 + 32768, 256);
    float* el   = (float*)(ws + off); off = align_up(off + (size_t)N * 2 * 4, 256);
    float* er   = (float*)(ws + off); off = align_up(off + (size_t)N * 2 * 4, 256);
    int* rowStart = (int*)(ws + off); off = align_up(off + (size_t)(N + 1) * 4, 256);
    int* csr      = (int*)(ws + off); off = align_up(off + (size_t)E * 4, 256);
    int* ebuf     = (int*)(ws + off); off = align_up(off + (size_t)E * 4, 256);
    int* bcnt     = (int*)(ws + off); off = align_up(off + (size_t)NBUCK * 4, 256);
    int* bbase    = (int*)(ws + off); off = align_up(off + (size_t)(NBUCK + 1) * 4, 256);
    int* bcursor  = (int*)(ws + off); off = align_up(off + (size_t)NBUCK * 4, 256);
    __half* wh1   = (__half*)(ws + off); off = align_up(off + (size_t)16384 * 2, 256);
    __half* wh2   = (__half*)(ws + off); off = align_up(off + (size_t)16384 * 2, 256);

    const int etile_grid = (E + ETILE - 1) / ETILE;
    const int gemm_grid = (N + 127) / 128;
    const int agg_grid = (N + 15) / 16;

    hipMemsetAsync(bcnt, 0, (size_t)NBUCK * 4, stream);
    k_prepcount<<<16 + etile_grid, 256, 0, stream>>>(W1, W2, wh1, wh2, dst, E, NBUCK, bcnt);
    k_bscan<<<1, 256, 0, stream>>>(bcnt, NBUCK, bbase, bcursor, rowStart, N, E);

    // gemm layer 1 with bucket side-job fused (bucket blocks scheduled first)
    k_gemm_fused<false, true><<<etile_grid + gemm_grid, 256, 0, stream>>>(
        x, wh1, hb, al1, ar1, el, er, N, src, dst, E, NBUCK, bcursor, ebuf, etile_grid);

    k_build<<<NBUCK, 256, 0, stream>>>(ebuf, bbase, rowStart, csr, N);

    k_agg<true, true><<<agg_grid, 256, 0, stream>>>(hb, el, er, rowStart, csr, b1, bufBh, N);

    k_gemm_fused<true, false><<<gemm_grid, 256, 0, stream>>>(
        bufBh, wh2, hb, al2, ar2, el, er, N, nullptr, nullptr, 0, 0, nullptr, nullptr, 0);

    k_agg<false, false><<<agg_grid, 256, 0, stream>>>(hb, el, er, rowStart, csr, b2, out, N);
}

// Round 13
// 223.452 us; speedup vs baseline: 1.0313x; 1.0313x over previous
//
#include <hip/hip_runtime.h>
#include <hip/hip_fp16.h>

// 2-layer GAT, H=2 heads, D=64 per head, F_IN=128.
// R13: R11 structure (64-row gemm, 3 blocks/CU) + build fused into a second
// gemm1 sub-dispatch: memset -> prepcount -> bscan -> [bucket ∥ gemm1A] ->
// [build ∥ gemm1B] -> agg1 -> gemm2 -> agg2.
// agg (pattern floor, ~69us): 4 nodes/wave, 16 lanes/node, unnormalized-exp
// records in LDS, 4-record gather batches.
// Assumes N <= 131072 (src packs in 17 bits) and NBUCK <= 512.

#define NEG_SLOPE 0.2f
#define BSHIFT 8
#define ETILE 4096

typedef _Float16 half8_t __attribute__((ext_vector_type(8)));
typedef float f32x4_t __attribute__((ext_vector_type(4)));
typedef unsigned long long u64;

// ---------------- prep (W transpose+fp16+pre-swizzle) + dst histogram ----------------

__global__ __launch_bounds__(256) void k_prepcount(const float* __restrict__ W1,
                                                   const float* __restrict__ W2,
                                                   __half* __restrict__ wh1,
                                                   __half* __restrict__ wh2,
                                                   const int* __restrict__ dst, int E,
                                                   int nbuck, int* __restrict__ bcnt) {
    int b = blockIdx.x;
    int t = threadIdx.x;
    if (b < 16) {
        const float* W = (b < 8) ? W1 : W2;
        __half* Wh = (b < 8) ? wh1 : wh2;
        int q = (b & 7) * 256 + t;
        int r = q >> 4;
        int c = q & 15;
        int cl = c ^ (r & 7);
        float f[8];
        #pragma unroll
        for (int j = 0; j < 8; j++) f[j] = W[(size_t)(cl * 8 + j) * 128 + r];
        __half2 h0 = __floats2half2_rn(f[0], f[1]);
        __half2 h1 = __floats2half2_rn(f[2], f[3]);
        __half2 h2 = __floats2half2_rn(f[4], f[5]);
        __half2 h3 = __floats2half2_rn(f[6], f[7]);
        uint4 pk;
        pk.x = *(unsigned*)&h0;
        pk.y = *(unsigned*)&h1;
        pk.z = *(unsigned*)&h2;
        pk.w = *(unsigned*)&h3;
        *(uint4*)((char*)Wh + (size_t)q * 16) = pk;
    } else {
        __shared__ int cnt[512];
        for (int i = t; i < nbuck; i += 256) cnt[i] = 0;
        __syncthreads();
        int e0 = (b - 16) * ETILE;
        #pragma unroll
        for (int j = 0; j < ETILE / 256; j++) {
            int e = e0 + j * 256 + t;
            if (e < E) atomicAdd(&cnt[dst[e] >> BSHIFT], 1);
        }
        __syncthreads();
        for (int i = t; i < nbuck; i += 256) {
            int c = cnt[i];
            if (c > 0) atomicAdd(&bcnt[i], c);
        }
    }
}

// ---------------- bucket scan ----------------

__global__ __launch_bounds__(256) void k_bscan(const int* __restrict__ bcnt, int nbuck,
                                               int* __restrict__ bbase,
                                               int* __restrict__ bcursor,
                                               int* __restrict__ rowStart, int N, int E) {
    __shared__ int sa[512], sb[512];
    int t = threadIdx.x;
    sa[t] = (t < nbuck) ? bcnt[t] : 0;
    sa[t + 256] = (t + 256 < nbuck) ? bcnt[t + 256] : 0;
    __syncthreads();
    int* a = sa;
    int* b = sb;
    for (int off = 1; off < 512; off <<= 1) {
        b[t] = a[t] + ((t >= off) ? a[t - off] : 0);
        int i = t + 256;
        b[i] = a[i] + ((i >= off) ? a[i - off] : 0);
        __syncthreads();
        int* tmp = a; a = b; b = tmp;
    }
    #pragma unroll
    for (int k = 0; k < 2; k++) {
        int i = t + k * 256;
        if (i <= nbuck) {
            int e_ = (i == 0) ? 0 : a[i - 1];
            bbase[i] = e_;
            if (i < nbuck) bcursor[i] = e_;
        }
    }
    if (t == 0) rowStart[N] = E;
}

// ---------------- fused MFMA GEMM (+ bucket or build side-job) ----------------

__device__ __forceinline__ void g2l16(const void* g, void* l) {
    __builtin_amdgcn_global_load_lds((const __attribute__((address_space(1))) void*)g,
                                     (__attribute__((address_space(3))) void*)l, 16, 0, 0);
}

// JOB: 0 = none, 1 = bucket side-blocks, 2 = build side-blocks
template <bool FP16IN, int JOB>
__global__ __launch_bounds__(256, 3) void k_gemm_fused(const void* __restrict__ Ain,
                                                       const __half* __restrict__ WhT,
                                                       __half* __restrict__ hb,
                                                       const float* __restrict__ al,
                                                       const float* __restrict__ ar,
                                                       float* __restrict__ el,
                                                       float* __restrict__ er, int M,
                                                       const int* __restrict__ srcE,
                                                       const int* __restrict__ dstE, int E,
                                                       int nbuck, int* __restrict__ bcursor,
                                                       int* __restrict__ ebuf,
                                                       const int* __restrict__ bbase,
                                                       int* __restrict__ rowStart,
                                                       int* __restrict__ csr,
                                                       int sideBlocks, int rowBase) {
    __shared__ __half xs[64 * 128];    // 16 KB, swizzled (side jobs alias this)
    __shared__ __half ws[128 * 128];   // 32 KB, swizzled (pre-swizzled source)
    int t = threadIdx.x;

    if (JOB == 1 && (int)blockIdx.x < sideBlocks) {
        // ---- bucket side-job ----
        int* cnt = (int*)xs;           // 512 ints
        int* base = cnt + 512;         // 512 ints
        for (int b = t; b < nbuck; b += 256) cnt[b] = 0;
        __syncthreads();
        int e0 = (int)blockIdx.x * ETILE;
        int dv[ETILE / 256], sv[ETILE / 256];
        #pragma unroll
        for (int j = 0; j < ETILE / 256; j++) {
            int e = e0 + j * 256 + t;
            dv[j] = -1;
            if (e < E) {
                dv[j] = dstE[e];
                sv[j] = srcE[e];
                atomicAdd(&cnt[dv[j] >> BSHIFT], 1);
            }
        }
        __syncthreads();
        for (int b = t; b < nbuck; b += 256) {
            int c = cnt[b];
            base[b] = (c > 0) ? atomicAdd(&bcursor[b], c) : 0;
        }
        __syncthreads();
        for (int b = t; b < nbuck; b += 256) cnt[b] = 0;
        __syncthreads();
        #pragma unroll
        for (int j = 0; j < ETILE / 256; j++) {
            if (dv[j] >= 0) {
                int bk = dv[j] >> BSHIFT;
                int r = atomicAdd(&cnt[bk], 1);
                ebuf[base[bk] + r] = sv[j] | ((dv[j] & ((1 << BSHIFT) - 1)) << 17);
            }
        }
        return;
    }

    if (JOB == 2 && (int)blockIdx.x < sideBlocks) {
        // ---- build side-job (per-bucket counting sort) ----
        int* dcnt = (int*)xs;
        int* sa = dcnt + 256;
        int* sb = sa + 256;
        int* cur = sb + 256;
        int b = blockIdx.x;
        int lo = bbase[b], hi2 = bbase[b + 1];
        int n0 = b << BSHIFT;
        dcnt[t] = 0;
        __syncthreads();
        for (int p = lo + t; p < hi2; p += 256)
            atomicAdd(&dcnt[((unsigned)ebuf[p]) >> 17], 1);
        __syncthreads();
        sa[t] = dcnt[t];
        __syncthreads();
        int* a = sa;
        int* bq = sb;
        for (int off2 = 1; off2 < 256; off2 <<= 1) {
            bq[t] = a[t] + ((t >= off2) ? a[t - off2] : 0);
            __syncthreads();
            int* tmp = a; a = bq; bq = tmp;
        }
        int excl = (t == 0) ? 0 : a[t - 1];
        int pos0 = lo + excl;
        if (n0 + t < M) rowStart[n0 + t] = pos0;
        cur[t] = pos0;
        __syncthreads();
        for (int p = lo + t; p < hi2; p += 256) {
            int v = ebuf[p];
            int pos = atomicAdd(&cur[((unsigned)v) >> 17], 1);
            csr[pos] = v & 0x1FFFF;
        }
        return;
    }

    int row0 = ((JOB ? ((int)blockIdx.x - sideBlocks) : (int)blockIdx.x) + rowBase) * 64;

    for (int j = 0; j < 8; j++) {
        int c16 = t + j * 256;
        g2l16((const char*)WhT + (size_t)c16 * 16, (char*)ws + (size_t)c16 * 16);
    }
    if (FP16IN) {
        const char* Ah = (const char*)Ain;   // pre-swizzled fp16 rows
        for (int j = 0; j < 4; j++) {
            int c16 = t + j * 256;
            g2l16(Ah + (size_t)row0 * 256 + (size_t)c16 * 16, (char*)xs + (size_t)c16 * 16);
        }
    } else {
        const float* A = (const float*)Ain;
        for (int j = 0; j < 8; j++) {
            int f4 = t + j * 256;
            int r = f4 >> 5;
            int gr = row0 + r;
            if (gr >= M) gr = M - 1;   // clamp; outputs guarded
            float4 v = ((const float4*)(A + (size_t)gr * 128))[f4 & 31];
            __half2 h0 = __floats2half2_rn(v.x, v.y);
            __half2 h1 = __floats2half2_rn(v.z, v.w);
            uint2 pk;
            pk.x = *(unsigned*)&h0;
            pk.y = *(unsigned*)&h1;
            int h8 = f4 & 31;
            int c = h8 >> 1, hh = h8 & 1;
            int addr8 = r * 32 + (c ^ (r & 7)) * 2 + hh;
            *(uint2*)((char*)xs + (size_t)addr8 * 8) = pk;
        }
    }
    __syncthreads();   // the only barrier

    int wid = t >> 6, lane = t & 63;
    int l15 = lane & 15;
    int g = lane >> 4;
    int mrow = wid * 16 + l15;

    half8_t xf[4];
    #pragma unroll
    for (int ks = 0; ks < 4; ks++) {
        int c = ks * 4 + g;
        xf[ks] = *(const half8_t*)((const char*)xs + mrow * 256 + (size_t)(c ^ (mrow & 7)) * 16);
    }

    f32x4_t acc[8];
    #pragma unroll
    for (int i = 0; i < 8; i++) acc[i] = (f32x4_t){0.f, 0.f, 0.f, 0.f};

    #pragma unroll
    for (int nt = 0; nt < 8; nt++) {
        int nrow = nt * 16 + l15;
        #pragma unroll
        for (int ks = 0; ks < 4; ks++) {
            int c = ks * 4 + g;
            half8_t wf = *(const half8_t*)((const char*)ws + nrow * 256 + (size_t)(c ^ (nrow & 7)) * 16);
            acc[nt] = __builtin_amdgcn_mfma_f32_16x16x32_f16(wf, xf[ks], acc[nt], 0, 0, 0);
        }
    }

    int m = row0 + mrow;
    bool valid = m < M;
    float plh0 = 0.f, prh0 = 0.f, plh1 = 0.f, prh1 = 0.f;
    #pragma unroll
    for (int nt = 0; nt < 8; nt++) {
        int col0 = nt * 16 + g * 4;
        if (valid) {
            __half2 p0 = __floats2half2_rn(acc[nt][0], acc[nt][1]);
            __half2 p1 = __floats2half2_rn(acc[nt][2], acc[nt][3]);
            uint2 pk;
            pk.x = *(unsigned*)&p0;
            pk.y = *(unsigned*)&p1;
            *(uint2*)(hb + (size_t)m * 128 + col0) = pk;
        }
        float4 alv = *(const float4*)(al + col0);
        float4 arv = *(const float4*)(ar + col0);
        float pl = acc[nt][0] * alv.x + acc[nt][1] * alv.y + acc[nt][2] * alv.z + acc[nt][3] * alv.w;
        float pr = acc[nt][0] * arv.x + acc[nt][1] * arv.y + acc[nt][2] * arv.z + acc[nt][3] * arv.w;
        if (nt < 4) { plh0 += pl; prh0 += pr; }
        else       { plh1 += pl; prh1 += pr; }
    }
    plh0 += __shfl_xor(plh0, 16); plh0 += __shfl_xor(plh0, 32);
    plh1 += __shfl_xor(plh1, 16); plh1 += __shfl_xor(plh1, 32);
    prh0 += __shfl_xor(prh0, 16); prh0 += __shfl_xor(prh0, 32);
    prh1 += __shfl_xor(prh1, 16); prh1 += __shfl_xor(prh1, 32);
    if (lane < 16 && valid) {
        el[m * 2 + 0] = plh0;
        el[m * 2 + 1] = plh1;
        er[m * 2 + 0] = prh0;
        er[m * 2 + 1] = prh1;
    }
}

// ---------------- aggregate (pattern-floor pinned; unchanged from R11) ----------------

__device__ __forceinline__ float h2f(__half h) { return __half2float(h); }

template <bool RELU, bool FP16OUT>
__global__ __launch_bounds__(256) void k_agg(const __half* __restrict__ hb,
                                             const float* __restrict__ el,
                                             const float* __restrict__ er,
                                             const int* __restrict__ rowStart,
                                             const int* __restrict__ csr,
                                             const float* __restrict__ bias,
                                             void* __restrict__ outv, int N) {
    __shared__ u64 albuf[4][4][65];
    int wid = threadIdx.x >> 6;
    int lane = threadIdx.x & 63;
    int q = lane >> 4;    // node slot
    int l = lane & 15;    // lane within node: dims 8l..8l+7
    int n = (blockIdx.x * 4 + wid) * 4 + q;
    bool active = n < N;

    int rs = 0, deg = 0;
    float2 erv = make_float2(0.f, 0.f);
    if (active) {
        rs = rowStart[n];
        deg = rowStart[n + 1] - rs;
        erv = ((const float2*)er)[n];
    }

    float s0 = 0.f, s1 = 0.f;
    if (active) {
        for (int i = l; i <= deg; i += 16) {
            int s = (i == deg) ? n : csr[rs + i];
            float2 ev = ((const float2*)el)[s];
            float e0 = ev.x + erv.x;
            e0 = (e0 >= 0.f) ? e0 : NEG_SLOPE * e0;
            float e1 = ev.y + erv.y;
            e1 = (e1 >= 0.f) ? e1 : NEG_SLOPE * e1;
            float ex0 = __expf(e0);
            float ex1 = __expf(e1);
            s0 += ex0;
            s1 += ex1;
            if (i < 64) {
                __half2 eh = __floats2half2_rn(ex0, ex1);
                albuf[wid][q][i] = ((u64)(*(unsigned*)&eh) << 32) | (u64)(unsigned)s;
            }
        }
    }
    #pragma unroll
    for (int mk = 8; mk >= 1; mk >>= 1) {
        s0 += __shfl_xor(s0, mk);
        s1 += __shfl_xor(s1, mk);
    }
    bool hi = l >= 8;
    float invh = hi ? (1.0f / s1) : (1.0f / s0);

    float a0 = 0.f, a1 = 0.f, a2 = 0.f, a3 = 0.f;
    float a4 = 0.f, a5 = 0.f, a6 = 0.f, a7 = 0.f;
    if (active) {
        int cnt = deg + 1;
        int jmax = (cnt < 64) ? cnt : 64;
        int j = 0;
        for (; j + 4 <= jmax; j += 4) {
            u64 r0 = albuf[wid][q][j + 0];
            u64 r1 = albuf[wid][q][j + 1];
            u64 r2 = albuf[wid][q][j + 2];
            u64 r3 = albuf[wid][q][j + 3];
            uint4 v0 = ((const uint4*)(hb + (size_t)(unsigned)r0 * 128))[l];
            uint4 v1 = ((const uint4*)(hb + (size_t)(unsigned)r1 * 128))[l];
            uint4 v2 = ((const uint4*)(hb + (size_t)(unsigned)r2 * 128))[l];
            uint4 v3 = ((const uint4*)(hb + (size_t)(unsigned)r3 * 128))[l];
            #pragma unroll
            for (int kk = 0; kk < 4; kk++) {
                u64 rec = (kk == 0) ? r0 : (kk == 1) ? r1 : (kk == 2) ? r2 : r3;
                uint4 hv = (kk == 0) ? v0 : (kk == 1) ? v1 : (kk == 2) ? v2 : v3;
                unsigned eb = (unsigned)(rec >> 32);
                __half hx;
                *(unsigned short*)&hx = (unsigned short)(hi ? (eb >> 16) : (eb & 0xffff));
                float a = h2f(hx);
                __half2 p0 = *(__half2*)&hv.x;
                __half2 p1 = *(__half2*)&hv.y;
                __half2 p2 = *(__half2*)&hv.z;
                __half2 p3 = *(__half2*)&hv.w;
                a0 += a * h2f(p0.x);  a1 += a * h2f(p0.y);
                a2 += a * h2f(p1.x);  a3 += a * h2f(p1.y);
                a4 += a * h2f(p2.x);  a5 += a * h2f(p2.y);
                a6 += a * h2f(p3.x);  a7 += a * h2f(p3.y);
            }
        }
        for (; j < jmax; ++j) {
            u64 rec = albuf[wid][q][j];
            unsigned eb = (unsigned)(rec >> 32);
            __half hx;
            *(unsigned short*)&hx = (unsigned short)(hi ? (eb >> 16) : (eb & 0xffff));
            float a = h2f(hx);
            uint4 hv = ((const uint4*)(hb + (size_t)(unsigned)rec * 128))[l];
            __half2 p0 = *(__half2*)&hv.x;
            __half2 p1 = *(__half2*)&hv.y;
            __half2 p2 = *(__half2*)&hv.z;
            __half2 p3 = *(__half2*)&hv.w;
            a0 += a * h2f(p0.x);  a1 += a * h2f(p0.y);
            a2 += a * h2f(p1.x);  a3 += a * h2f(p1.y);
            a4 += a * h2f(p2.x);  a5 += a * h2f(p2.y);
            a6 += a * h2f(p3.x);  a7 += a * h2f(p3.y);
        }
        for (int jj = 64; jj < cnt; ++jj) {   // rare tail (deg >= 64)
            int s = (jj == deg) ? n : csr[rs + jj];
            float2 ev = ((const float2*)el)[s];
            float e = hi ? (ev.y + erv.y) : (ev.x + erv.x);
            e = (e >= 0.f) ? e : NEG_SLOPE * e;
            float a = __expf(e);
            uint4 hv = ((const uint4*)(hb + (size_t)s * 128))[l];
            __half2 p0 = *(__half2*)&hv.x;
            __half2 p1 = *(__half2*)&hv.y;
            __half2 p2 = *(__half2*)&hv.z;
            __half2 p3 = *(__half2*)&hv.w;
            a0 += a * h2f(p0.x);  a1 += a * h2f(p0.y);
            a2 += a * h2f(p1.x);  a3 += a * h2f(p1.y);
            a4 += a * h2f(p2.x);  a5 += a * h2f(p2.y);
            a6 += a * h2f(p3.x);  a7 += a * h2f(p3.y);
        }

        const float4* bp = (const float4*)(bias + l * 8);
        float4 b0 = bp[0], b1 = bp[1];
        a0 = a0 * invh + b0.x;  a1 = a1 * invh + b0.y;
        a2 = a2 * invh + b0.z;  a3 = a3 * invh + b0.w;
        a4 = a4 * invh + b1.x;  a5 = a5 * invh + b1.y;
        a6 = a6 * invh + b1.z;  a7 = a7 * invh + b1.w;
        if (RELU) {
            a0 = fmaxf(a0, 0.f); a1 = fmaxf(a1, 0.f); a2 = fmaxf(a2, 0.f); a3 = fmaxf(a3, 0.f);
            a4 = fmaxf(a4, 0.f); a5 = fmaxf(a5, 0.f); a6 = fmaxf(a6, 0.f); a7 = fmaxf(a7, 0.f);
        }
        if (FP16OUT) {
            __half2 q0 = __floats2half2_rn(a0, a1);
            __half2 q1 = __floats2half2_rn(a2, a3);
            __half2 q2 = __floats2half2_rn(a4, a5);
            __half2 q3 = __floats2half2_rn(a6, a7);
            uint4 opk;
            opk.x = *(unsigned*)&q0;
            opk.y = *(unsigned*)&q1;
            opk.z = *(unsigned*)&q2;
            opk.w = *(unsigned*)&q3;
            ((uint4*)((__half*)outv + (size_t)n * 128))[l ^ (n & 7)] = opk;
        } else {
            float* op = (float*)outv + (size_t)n * 128 + l * 8;
            ((float4*)op)[0] = make_float4(a0, a1, a2, a3);
            ((float4*)op)[1] = make_float4(a4, a5, a6, a7);
        }
    }
}

// ---------------- launcher ----------------

static inline size_t align_up(size_t v, size_t a) { return (v + a - 1) & ~(a - 1); }

extern "C" void kernel_launch(void* const* d_in, const int* in_sizes, int n_in,
                              void* d_out, int out_size, void* d_ws, size_t ws_size,
                              hipStream_t stream) {
    const float* x   = (const float*)d_in[0];
    const int*   src = (const int*)d_in[1];
    const int*   dst = (const int*)d_in[2];
    const float* W1  = (const float*)d_in[3];
    const float* al1 = (const float*)d_in[4];
    const float* ar1 = (const float*)d_in[5];
    const float* b1  = (const float*)d_in[6];
    const float* W2  = (const float*)d_in[7];
    const float* al2 = (const float*)d_in[8];
    const float* ar2 = (const float*)d_in[9];
    const float* b2  = (const float*)d_in[10];
    float* out = (float*)d_out;

    const int N = in_sizes[0] / 128;
    const int E = in_sizes[1];
    const int NBUCK = (N + 255) >> 8;

    char* ws = (char*)d_ws;
    size_t off = 0;
    __half* bufBh = (__half*)(ws + off); off = align_up(off + (size_t)N * 128 * 2, 256);
    __half* hb    = (__half*)(ws + off); off = align_up(off + (size_t)N * 128 * 2 + 16384, 256);
    float* el   = (float*)(ws + off); off = align_up(off + (size_t)N * 2 * 4, 256);
    float* er   = (float*)(ws + off); off = align_up(off + (size_t)N * 2 * 4, 256);
    int* rowStart = (int*)(ws + off); off = align_up(off + (size_t)(N + 1) * 4, 256);
    int* csr      = (int*)(ws + off); off = align_up(off + (size_t)E * 4, 256);
    int* ebuf     = (int*)(ws + off); off = align_up(off + (size_t)E * 4, 256);
    int* bcnt     = (int*)(ws + off); off = align_up(off + (size_t)NBUCK * 4, 256);
    int* bbase    = (int*)(ws + off); off = align_up(off + (size_t)(NBUCK + 1) * 4, 256);
    int* bcursor  = (int*)(ws + off); off = align_up(off + (size_t)NBUCK * 4, 256);
    __half* wh1   = (__half*)(ws + off); off = align_up(off + (size_t)16384 * 2, 256);
    __half* wh2   = (__half*)(ws + off); off = align_up(off + (size_t)16384 * 2, 256);

    const int etile_grid = (E + ETILE - 1) / ETILE;
    const int gemm_grid = (N + 63) / 64;
    const int gA = (gemm_grid + 1) / 2;        // gemm1 part A blocks
    const int gB = gemm_grid - gA;             // gemm1 part B blocks
    const int agg_grid = (N + 15) / 16;

    hipMemsetAsync(bcnt, 0, (size_t)NBUCK * 4, stream);
    k_prepcount<<<16 + etile_grid, 256, 0, stream>>>(W1, W2, wh1, wh2, dst, E, NBUCK, bcnt);
    k_bscan<<<1, 256, 0, stream>>>(bcnt, NBUCK, bbase, bcursor, rowStart, N, E);

    // gemm1 part A ∥ bucket (bucket blocks first)
    k_gemm_fused<false, 1><<<etile_grid + gA, 256, 0, stream>>>(
        x, wh1, hb, al1, ar1, el, er, N, src, dst, E, NBUCK, bcursor, ebuf,
        nullptr, nullptr, nullptr, etile_grid, 0);

    // gemm1 part B ∥ build (build blocks first; depends on bucket via prior dispatch)
    k_gemm_fused<false, 2><<<NBUCK + gB, 256, 0, stream>>>(
        x, wh1, hb, al1, ar1, el, er, N, nullptr, nullptr, 0, NBUCK, nullptr, ebuf,
        bbase, rowStart, csr, NBUCK, gA);

    k_agg<true, true><<<agg_grid, 256, 0, stream>>>(hb, el, er, rowStart, csr, b1, bufBh, N);

    k_gemm_fused<true, 0><<<gemm_grid, 256, 0, stream>>>(
        bufBh, wh2, hb, al2, ar2, el, er, N, nullptr, nullptr, 0, 0, nullptr, nullptr,
        nullptr, nullptr, nullptr, 0, 0);

    k_agg<false, false><<<agg_grid, 256, 0, stream>>>(hb, el, er, rowStart, csr, b2, out, N);
}